// Round 13
// baseline (239.891 us; speedup 1.0000x reference)
//
#include <hip/hip_runtime.h>

#define S 4096
#define BATCH 2
#define D 768
#define NH 12
#define DH 64
#define NROWS (BATCH * S)
#define CTR_OFF 67633152                   // byte offset of queue counter in ws

// split-K attention queue: items qt>=24 split into 2 key-range halves.
//  p in [0,216)   : unsplit qt = 23 - p/24          (len 48..32)
//  p in [216,600) : halves  qt = 31 - (p-216)/48    (len 32..25)
//  p in [600,960) : unsplit qt = 14 - (p-600)/24    (len 30..2)
#define N_ITEMS 960
#define NSPLIT 192                         // 8 qt values x 24 (h,b)

typedef __attribute__((ext_vector_type(8))) short bf16x8;   // 8 bf16 (4 VGPRs)
typedef __attribute__((ext_vector_type(4))) float f32x4;
typedef __attribute__((ext_vector_type(2))) unsigned uint32x2;

__device__ __forceinline__ unsigned short f2bf(float f) {
    unsigned u = __builtin_bit_cast(unsigned, f);
    u += 0x7fff + ((u >> 16) & 1);          // round-to-nearest-even
    return (unsigned short)(u >> 16);
}

__device__ __forceinline__ float fexp2(float x) {
#if __has_builtin(__builtin_amdgcn_exp2f)
    return __builtin_amdgcn_exp2f(x);       // raw v_exp_f32
#else
    return exp2f(x);
#endif
}

// async global->LDS, 16B per lane; lds ptr must be wave-uniform
#define GLDS16(g, l)                                                   \
    __builtin_amdgcn_global_load_lds(                                  \
        (const __attribute__((address_space(1))) void*)(g),            \
        (__attribute__((address_space(3))) void*)(l), 16, 0, 0)

// ---------------------------------------------------------------------------
// x (fp32 [8192][768]) -> bf16. grid 6144 x 256.
// ---------------------------------------------------------------------------
__global__ __launch_bounds__(256) void cvt_x(const float* __restrict__ x,
                                             unsigned short* __restrict__ xb)
{
    int i = (blockIdx.x * 256 + threadIdx.x) * 4;
    float4 v = *(const float4*)(x + i);
    ushort4 o = make_ushort4(f2bf(v.x), f2bf(v.y), f2bf(v.z), f2bf(v.w));
    *(ushort4*)(xb + i) = o;
}

// ---------------------------------------------------------------------------
// W[k][n] fp32 -> wt[z][n][k] bf16 (transposed), z in {Wq,Wk,Wv,Wo}.
// grid (24, 24, 4) x 256; 32x32 LDS tile.
// ---------------------------------------------------------------------------
__global__ __launch_bounds__(256) void cvt_w(
    const float* __restrict__ Wq, const float* __restrict__ Wk,
    const float* __restrict__ Wv, const float* __restrict__ Wo,
    unsigned short* __restrict__ wt)
{
    __shared__ float tile[32][33];
    const int z = blockIdx.z;
    const float* W = (z == 0) ? Wq : (z == 1) ? Wk : (z == 2) ? Wv : Wo;
    const int k0 = blockIdx.x * 32, n0 = blockIdx.y * 32;
    const int t = threadIdx.x;
    const int r = t >> 3, c4 = (t & 7) * 4;

    float4 v = *(const float4*)(W + (size_t)(k0 + r) * D + n0 + c4);
    tile[r][c4 + 0] = v.x; tile[r][c4 + 1] = v.y;
    tile[r][c4 + 2] = v.z; tile[r][c4 + 3] = v.w;
    __syncthreads();
    ushort4 o = make_ushort4(f2bf(tile[c4 + 0][r]), f2bf(tile[c4 + 1][r]),
                             f2bf(tile[c4 + 2][r]), f2bf(tile[c4 + 3][r]));
    *(ushort4*)(wt + ((size_t)z * D + n0 + r) * D + k0 + c4) = o;
}

// ---------------------------------------------------------------------------
// QKV GEMM, bf16 MFMA. A = xb [8192][768], B = wt[z][n][k] (z = n0/768).
// 128x128 tile, BK=64, global_load_lds staging with XOR-8 swizzle.
// Q is pre-scaled by 0.125*log2(e) so attention softmax can use exp2.
// grid (64, 18).
// ---------------------------------------------------------------------------
__global__ __launch_bounds__(256) void gemm_qkv(
    const unsigned short* __restrict__ xb,
    const unsigned short* __restrict__ wt,
    unsigned short* __restrict__ qb, unsigned short* __restrict__ kb,
    unsigned short* __restrict__ vtb)
{
    __shared__ unsigned short As[128 * 64];
    __shared__ unsigned short Bs[128 * 64];

    const int t = threadIdx.x;
    const int lane = t & 63, w = t >> 6;
    const int l16 = lane & 15, quad = lane >> 4;
    const int wm = w & 1, wn = w >> 1;
    const int m0 = blockIdx.x * 128;
    const int n0g = blockIdx.y * 128;
    const int z = n0g / 768;
    const int c0 = n0g - z * 768;
    const unsigned short* Wz = wt + (size_t)z * D * D;

    f32x4 acc[4][4] = {};

    for (int k0 = 0; k0 < D; k0 += 64) {
#pragma unroll
        for (int i = 0; i < 4; ++i) {
            int g = i * 256 + w * 64 + lane;
            int row = g >> 3, cl = g & 7, cg = cl ^ (row & 7);
            GLDS16(xb + (size_t)(m0 + row) * D + k0 + cg * 8,
                   As + (size_t)(i * 256 + w * 64) * 8);
            GLDS16(Wz + (size_t)(c0 + row) * D + k0 + cg * 8,
                   Bs + (size_t)(i * 256 + w * 64) * 8);
        }
        __syncthreads();
#pragma unroll
        for (int kk = 0; kk < 2; ++kk) {
            bf16x8 af[4], bf_[4];
#pragma unroll
            for (int mt = 0; mt < 4; ++mt) {
                int r = wm * 64 + mt * 16 + l16;
                int c = kk * 4 + quad;
                af[mt] = *(const bf16x8*)&As[(r * 8 + (c ^ (r & 7))) * 8];
            }
#pragma unroll
            for (int nt = 0; nt < 4; ++nt) {
                int r = wn * 64 + nt * 16 + l16;
                int c = kk * 4 + quad;
                bf_[nt] = *(const bf16x8*)&Bs[(r * 8 + (c ^ (r & 7))) * 8];
            }
#pragma unroll
            for (int mt = 0; mt < 4; ++mt)
#pragma unroll
                for (int nt = 0; nt < 4; ++nt)
                    acc[mt][nt] = __builtin_amdgcn_mfma_f32_16x16x32_bf16(
                        af[mt], bf_[nt], acc[mt][nt], 0, 0, 0);
        }
        __syncthreads();
    }

    if (z < 2) {
        unsigned short* outp = (z == 0) ? qb : kb;
        const float scale = (z == 0) ? 0.18033688011112042f : 1.0f; // .125*log2e
#pragma unroll
        for (int mt = 0; mt < 4; ++mt) {
#pragma unroll
            for (int reg = 0; reg < 4; ++reg) {
                int m = wm * 64 + mt * 16 + quad * 4 + reg;
                int ng = m0 + m;
                int b = ng >> 12, s = ng & 4095;
#pragma unroll
                for (int nt = 0; nt < 4; ++nt) {
                    int n = c0 + wn * 64 + nt * 16 + l16;
                    int h = n >> 6, dh = n & 63;
                    outp[(((size_t)b * NH + h) * S + s) * DH + dh] =
                        f2bf(acc[mt][nt][reg] * scale);
                }
            }
        }
    } else {
#pragma unroll
        for (int mt = 0; mt < 4; ++mt) {
#pragma unroll
            for (int nt = 0; nt < 4; ++nt) {
                int m = wm * 64 + mt * 16 + quad * 4;
                int ng = m0 + m;
                int b = ng >> 12, s = ng & 4095;
                int n = c0 + wn * 64 + nt * 16 + l16;
                int h = n >> 6, dh = n & 63;
                ushort4 p = make_ushort4(
                    f2bf(acc[mt][nt][0]), f2bf(acc[mt][nt][1]),
                    f2bf(acc[mt][nt][2]), f2bf(acc[mt][nt][3]));
                *(ushort4*)(vtb + (((size_t)b * NH + h) * DH + dh) * S + s) = p;
            }
        }
    }
}

// ---------------------------------------------------------------------------
// Flash attention v19: v12's verified tile loop + split-K long items.
//  Makespan theory: 25344 tile-units / 512 blocks = 49.5 avg, but qt=31
//  items are 64 tiles (indivisible straggler, +29%). Fixed-max softmax is
//  LINEAR over key tiles (P = exp2(S) absolute, no max): split qt>=24
//  items into two key-range halves; each writes partial unnormalized fp32
//  O^T + partial row sums; a tiny combine kernel does (O0+O1)/(s0+s1).
//  New longest item = 48 < avg -> makespan ~52-56 units.
//  Partials live in RECYCLED ws: xb (dead after gemm_qkv, exactly 12.58MB
//  = Opart size) and wt[0] region (dead, holds Spart). Stream order
//  guarantees safety; cvt_x/cvt_w rewrite both every iteration.
//  Tile loop is v12's code verbatim with j in [jlo,jhi] (parity j&1
//  unchanged; mask uses absolute j, uniformly false in half 0).
// ---------------------------------------------------------------------------
__global__ __launch_bounds__(512, 4) void attn_mfma(
    const unsigned short* __restrict__ qg,
    const unsigned short* __restrict__ kg,
    const unsigned short* __restrict__ vtg,
    unsigned short* __restrict__ ctxb,
    float* __restrict__ Opart,         // [2][192][128][64] fp32
    float* __restrict__ Spart,         // [2][192][128] fp32
    int* __restrict__ work_ctr)
{
    __shared__ unsigned short Ks[2][64 * 64];  // [key][dh], XOR-8 swizzle
    __shared__ unsigned short Vs[2][64 * 64];  // [dh][key], XOR-8 swizzle
    __shared__ int s_item;

    const float INF = __builtin_inff();
    const int t = threadIdx.x;
    const int w = t >> 6, lane = t & 63;
    const int l16 = lane & 15, quad = lane >> 4;
    const int a7 = l16 & 7;
    // staging: 512 threads cover 64 rows x 8 col-segments in one GLDS16
    const int srow = t >> 3;
    const int scg = (t & 7) ^ (srow & 7);

    bf16x8 vone;
#pragma unroll
    for (int i = 0; i < 8; ++i) vone[i] = (short)0x3F80;   // bf16 1.0

    for (;;) {
        if (t == 0) s_item = atomicAdd(work_ctr, 1);
        __syncthreads();                 // broadcast item; prior LDS reads done
        const int p = s_item;
        if (p >= N_ITEMS) return;        // uniform exit

        // ---- queue decode (longest-first; see table at top) ----
        int qt, hb, jlo, jhi, half = 0;
        bool partial;
        if (p < 216)      { qt = 23 - p / 24; hb = p % 24;
                            jlo = 0; jhi = 2 * qt + 1; partial = false; }
        else if (p < 600) { int q = p - 216; qt = 31 - q / 48;
                            int r = q % 48; half = r / 24; hb = r % 24;
                            partial = true;
                            jlo = half ? qt + 1 : 0;
                            jhi = half ? 2 * qt + 1 : qt; }
        else              { int q = p - 600; qt = 14 - q / 24; hb = q % 24;
                            jlo = 0; jhi = 2 * qt + 1; partial = false; }
        const int h = hb % NH, b = hb / NH;
        const int jd = 2 * qt;
        const size_t hbase = ((size_t)b * NH + h) * (size_t)S * DH;
        const unsigned short* kp = kg + hbase;
        const unsigned short* vp = vtg + hbase;

        // this wave's 16 q-rows; Q^T B-fragments (reused across all tiles)
        const int qrow = qt * 128 + w * 16 + l16;
        bf16x8 bq[2];
#pragma unroll
        for (int kk = 0; kk < 2; ++kk)
            bq[kk] = *(const bf16x8*)(qg + hbase + (size_t)qrow * DH +
                                      kk * 32 + quad * 8);

        f32x4 acc_o[4] = {};             // O^T: row = dh-local, col = qrow = l16
        f32x4 acc_sum = {};              // row sums via ones-MFMA (replicated)

        // preload tile jlo into buffer jlo&1
        GLDS16(kp + (size_t)(jlo * 64 + srow) * DH + scg * 8,
               &Ks[jlo & 1][(size_t)w * 64 * 8]);
        GLDS16(vp + (size_t)srow * S + jlo * 64 + scg * 8,
               &Vs[jlo & 1][(size_t)w * 64 * 8]);

        for (int j = jlo; j <= jhi; ++j) {
            const int cur = j & 1;
            __syncthreads();             // drains tile-j loads; buf cur^1 free
            if (j < jhi) {               // prefetch j+1, overlaps compute
                GLDS16(kp + (size_t)((j + 1) * 64 + srow) * DH + scg * 8,
                       &Ks[cur ^ 1][(size_t)w * 64 * 8]);
                GLDS16(vp + (size_t)srow * S + (j + 1) * 64 + scg * 8,
                       &Vs[cur ^ 1][(size_t)w * 64 * 8]);
            }

            const unsigned short* Kc = Ks[cur];
            const unsigned short* Vc = Vs[cur];

            // --- S^T = K Q^T (one 16-row strip) ---
            f32x4 acc_s[4] = {};
            __builtin_amdgcn_s_setprio(1);
#pragma unroll
            for (int kk = 0; kk < 2; ++kk)
#pragma unroll
                for (int ms = 0; ms < 4; ++ms) {
                    int r = ms * 16 + l16, c = kk * 4 + quad;
                    bf16x8 ak = *(const bf16x8*)&Kc[(r * 8 + (c ^ a7)) * 8];
                    acc_s[ms] = __builtin_amdgcn_mfma_f32_16x16x32_bf16(
                        ak, bq[kk], acc_s[ms], 0, 0, 0);
                }
            __builtin_amdgcn_s_setprio(0);

            // --- causal mask: only the 2 diagonal tiles (uniform branch) ---
            if (j >= jd) {
#pragma unroll
                for (int ms = 0; ms < 4; ++ms)
#pragma unroll
                    for (int reg = 0; reg < 4; ++reg)
                        if ((j * 64 + ms * 16 + quad * 4 + reg) > qrow)
                            acc_s[ms][reg] = -INF;   // exp2 -> 0
            }

            // --- fixed-max softmax: P = exp2(S); pack + permlane -> bp ---
            bf16x8 bp[2];
            {
                unsigned ulo[4], uhi[4];
#pragma unroll
                for (int ms = 0; ms < 4; ++ms) {
                    float e0 = fexp2(acc_s[ms][0]);
                    float e1 = fexp2(acc_s[ms][1]);
                    float e2 = fexp2(acc_s[ms][2]);
                    float e3 = fexp2(acc_s[ms][3]);
                    asm("v_cvt_pk_bf16_f32 %0, %1, %2"
                        : "=v"(ulo[ms]) : "v"(e0), "v"(e1));
                    asm("v_cvt_pk_bf16_f32 %0, %1, %2"
                        : "=v"(uhi[ms]) : "v"(e2), "v"(e3));
                }
#pragma unroll
                for (int kp2 = 0; kp2 < 2; ++kp2) {
                    uint32x2 lo = __builtin_amdgcn_permlane32_swap(
                        ulo[2 * kp2], ulo[2 * kp2 + 1], false, false);
                    uint32x2 s02 = __builtin_amdgcn_permlane16_swap(
                        lo[0], lo[1], false, false);
                    uint32x2 hi = __builtin_amdgcn_permlane32_swap(
                        uhi[2 * kp2], uhi[2 * kp2 + 1], false, false);
                    uint32x2 s13 = __builtin_amdgcn_permlane16_swap(
                        hi[0], hi[1], false, false);
                    union { unsigned u[4]; bf16x8 v; } pb;
                    pb.u[0] = s02[0]; pb.u[1] = s13[0];
                    pb.u[2] = s02[1]; pb.u[3] = s13[1];
                    bp[kp2] = pb.v;
                }
            }

            // --- O^T += V^T P^T; row sums via ones-MFMA ---
            __builtin_amdgcn_s_setprio(1);
#pragma unroll
            for (int kk = 0; kk < 2; ++kk) {
#pragma unroll
                for (int d = 0; d < 4; ++d) {
                    int r = d * 16 + l16, c = kk * 4 + quad;
                    bf16x8 av = *(const bf16x8*)&Vc[(r * 8 + (c ^ a7)) * 8];
                    acc_o[d] = __builtin_amdgcn_mfma_f32_16x16x32_bf16(
                        av, bp[kk], acc_o[d], 0, 0, 0);
                }
                acc_sum = __builtin_amdgcn_mfma_f32_16x16x32_bf16(
                    vone, bp[kk], acc_sum, 0, 0, 0);
            }
            __builtin_amdgcn_s_setprio(0);
        }

        // --- epilogue ---
        if (!partial) {                  // normalize + write bf16 ctx
            float inv = 1.f / acc_sum[0];
            size_t base = ((size_t)(b * S + qrow)) * D + h * 64;
#pragma unroll
            for (int d = 0; d < 4; ++d) {
                ushort4 o;
                o.x = f2bf(acc_o[d][0] * inv);
                o.y = f2bf(acc_o[d][1] * inv);
                o.z = f2bf(acc_o[d][2] * inv);
                o.w = f2bf(acc_o[d][3] * inv);
                *(ushort4*)(ctxb + base + d * 16 + quad * 4) = o;
            }
        } else {                         // unnormalized fp32 partials
            int sid = (31 - qt) * 24 + hb;
            int qr = w * 16 + l16;
            float* Op = Opart + ((size_t)(half * NSPLIT + sid)) * (128 * 64)
                              + (size_t)qr * 64;
#pragma unroll
            for (int d = 0; d < 4; ++d)
#pragma unroll
                for (int reg = 0; reg < 4; ++reg)
                    Op[d * 16 + quad * 4 + reg] = acc_o[d][reg];
            if (quad == 0)
                Spart[(size_t)(half * NSPLIT + sid) * 128 + qr] = acc_sum[0];
        }
    }
}

// ---------------------------------------------------------------------------
// Combine split-item halves: ctx = (O0+O1)/(s0+s1). grid NSPLIT x 256.
// ---------------------------------------------------------------------------
__global__ __launch_bounds__(256) void attn_combine(
    const float* __restrict__ Opart, const float* __restrict__ Spart,
    unsigned short* __restrict__ ctxb)
{
    const int sid = blockIdx.x;
    const int qt = 31 - sid / 24, hb = sid % 24;
    const int h = hb % NH, b = hb / NH;
    const int t = threadIdx.x;
    const float* O0 = Opart + (size_t)sid * 8192;
    const float* O1 = Opart + (size_t)(NSPLIT + sid) * 8192;
    const float* S0 = Spart + (size_t)sid * 128;
    const float* S1 = Spart + (size_t)(NSPLIT + sid) * 128;

#pragma unroll
    for (int i = 0; i < 32; ++i) {
        int e = i * 256 + t;
        int qr = e >> 6, dh = e & 63;
        float inv = 1.f / (S0[qr] + S1[qr]);
        float v = (O0[e] + O1[e]) * inv;
        ctxb[((size_t)(b * S + qt * 128 + qr)) * D + h * 64 + dh] = f2bf(v);
    }
}

// ---------------------------------------------------------------------------
// Output projection, bf16 MFMA. A = ctxb [8192][768], B = wt[3] (Wo^T),
// +bias, fp32 out. v18: 128x64 tiles -> grid (64,12) = 768 blocks = 3/CU
// even (384 was 1.5/CU). LDS 24KB; ctxb refetch is L2/L3-resident.
// ---------------------------------------------------------------------------
__global__ __launch_bounds__(256) void gemm_out(
    const unsigned short* __restrict__ ctxb,
    const unsigned short* __restrict__ wt,
    const float* __restrict__ bo,
    float* __restrict__ out)
{
    __shared__ unsigned short As[128 * 64];   // 16 KB
    __shared__ unsigned short Bs[64 * 64];    // 8 KB

    const int t = threadIdx.x;
    const int lane = t & 63, w = t >> 6;
    const int l16 = lane & 15, quad = lane >> 4;
    const int m0 = blockIdx.x * 128;
    const int n0 = blockIdx.y * 64;
    const unsigned short* Wz = wt + (size_t)3 * D * D;

    f32x4 acc[2][4] = {};

    for (int k0 = 0; k0 < D; k0 += 64) {
#pragma unroll
        for (int i = 0; i < 4; ++i) {
            int g = i * 256 + w * 64 + lane;
            int row = g >> 3, cl = g & 7, cg = cl ^ (row & 7);
            GLDS16(ctxb + (size_t)(m0 + row) * D + k0 + cg * 8,
                   As + (size_t)(i * 256 + w * 64) * 8);
            if (i < 2)
                GLDS16(Wz + (size_t)(n0 + row) * D + k0 + cg * 8,
                       Bs + (size_t)(i * 256 + w * 64) * 8);
        }
        __syncthreads();
#pragma unroll
        for (int kk = 0; kk < 2; ++kk) {
            bf16x8 af[2], bf_[4];
#pragma unroll
            for (int mt = 0; mt < 2; ++mt) {
                int r = w * 32 + mt * 16 + l16;
                int c = kk * 4 + quad;
                af[mt] = *(const bf16x8*)&As[(r * 8 + (c ^ (r & 7))) * 8];
            }
#pragma unroll
            for (int nt = 0; nt < 4; ++nt) {
                int r = nt * 16 + l16;
                int c = kk * 4 + quad;
                bf_[nt] = *(const bf16x8*)&Bs[(r * 8 + (c ^ (r & 7))) * 8];
            }
#pragma unroll
            for (int mt = 0; mt < 2; ++mt)
#pragma unroll
                for (int nt = 0; nt < 4; ++nt)
                    acc[mt][nt] = __builtin_amdgcn_mfma_f32_16x16x32_bf16(
                        af[mt], bf_[nt], acc[mt][nt], 0, 0, 0);
        }
        __syncthreads();
    }

    float bv[4];
#pragma unroll
    for (int nt = 0; nt < 4; ++nt)
        bv[nt] = bo[n0 + nt * 16 + l16];
#pragma unroll
    for (int mt = 0; mt < 2; ++mt)
#pragma unroll
        for (int reg = 0; reg < 4; ++reg) {
            int m = m0 + w * 32 + mt * 16 + quad * 4 + reg;
#pragma unroll
            for (int nt = 0; nt < 4; ++nt)
                out[(size_t)m * D + n0 + nt * 16 + l16] =
                    acc[mt][nt][reg] + bv[nt];
        }
}

extern "C" void kernel_launch(void* const* d_in, const int* in_sizes, int n_in,
                              void* d_out, int out_size, void* d_ws, size_t ws_size,
                              hipStream_t stream)
{
    const float* x  = (const float*)d_in[0];
    const float* Wq = (const float*)d_in[1];
    const float* Wk = (const float*)d_in[2];
    const float* Wv = (const float*)d_in[3];
    const float* Wo = (const float*)d_in[4];
    const float* bo = (const float*)d_in[5];
    float* out = (float*)d_out;

    const size_t elems = (size_t)NROWS * D;     // 6,291,456
    unsigned short* xb   = (unsigned short*)d_ws;
    unsigned short* wt   = xb + elems;          // 4 * 768 * 768
    unsigned short* q    = wt + (size_t)4 * D * D;
    unsigned short* k    = q + elems;
    unsigned short* vt   = k + elems;
    unsigned short* ctxb = vt + elems;          // ends at byte 67,633,152
    int* work_ctr = (int*)((char*)d_ws + CTR_OFF);
    // split-K partials recycle dead regions (after gemm_qkv completes):
    //   Opart = xb region, exactly 2*192*128*64*4 = 12,582,912 B = xb size
    //   Spart = wt[0] region (2*192*128*4 = 196,608 B << 1,179,648 B)
    float* Opart = (float*)xb;
    float* Spart = (float*)wt;

    hipMemsetAsync(work_ctr, 0, sizeof(int), stream);

    cvt_x<<<NROWS * D / 1024, 256, 0, stream>>>(x, xb);
    dim3 gw(D / 32, D / 32, 4);
    cvt_w<<<gw, 256, 0, stream>>>(Wq, Wk, Wv, Wo, wt);

    dim3 g1(NROWS / 128, (3 * D) / 128);
    gemm_qkv<<<g1, 256, 0, stream>>>(xb, wt, q, k, vt);

    attn_mfma<<<512, 512, 0, stream>>>(q, k, vt, ctxb, Opart, Spart, work_ctr);
    attn_combine<<<NSPLIT, 256, 0, stream>>>(Opart, Spart, ctxb);

    dim3 g3(NROWS / 128, D / 64);
    gemm_out<<<g3, 256, 0, stream>>>(ctxb, wt, bo, out);
}

// Round 14
// 232.638 us; speedup vs baseline: 1.0312x; 1.0312x over previous
//
#include <hip/hip_runtime.h>

#define S 4096
#define BATCH 2
#define D 768
#define NH 12
#define DH 64
#define NROWS (BATCH * S)
#define N_ITEMS (32 * NH * BATCH)          // 768 (qt, h, b) work items
#define CTR_OFF 67633152                   // byte offset of queue counter in ws

typedef __attribute__((ext_vector_type(8))) short bf16x8;   // 8 bf16 (4 VGPRs)
typedef __attribute__((ext_vector_type(4))) float f32x4;
typedef __attribute__((ext_vector_type(2))) unsigned uint32x2;

__device__ __forceinline__ unsigned short f2bf(float f) {
    unsigned u = __builtin_bit_cast(unsigned, f);
    u += 0x7fff + ((u >> 16) & 1);          // round-to-nearest-even
    return (unsigned short)(u >> 16);
}

__device__ __forceinline__ float fexp2(float x) {
#if __has_builtin(__builtin_amdgcn_exp2f)
    return __builtin_amdgcn_exp2f(x);       // raw v_exp_f32
#else
    return exp2f(x);
#endif
}

// async global->LDS, 16B per lane; lds ptr must be wave-uniform
#define GLDS16(g, l)                                                   \
    __builtin_amdgcn_global_load_lds(                                  \
        (const __attribute__((address_space(1))) void*)(g),            \
        (__attribute__((address_space(3))) void*)(l), 16, 0, 0)

// ---------------------------------------------------------------------------
// x (fp32 [8192][768]) -> bf16. grid 6144 x 256.
// ---------------------------------------------------------------------------
__global__ __launch_bounds__(256) void cvt_x(const float* __restrict__ x,
                                             unsigned short* __restrict__ xb)
{
    int i = (blockIdx.x * 256 + threadIdx.x) * 4;
    float4 v = *(const float4*)(x + i);
    ushort4 o = make_ushort4(f2bf(v.x), f2bf(v.y), f2bf(v.z), f2bf(v.w));
    *(ushort4*)(xb + i) = o;
}

// ---------------------------------------------------------------------------
// W[k][n] fp32 -> wt[z][n][k] bf16 (transposed), z in {Wq,Wk,Wv,Wo}.
// grid (24, 24, 4) x 256; 32x32 LDS tile.
// ---------------------------------------------------------------------------
__global__ __launch_bounds__(256) void cvt_w(
    const float* __restrict__ Wq, const float* __restrict__ Wk,
    const float* __restrict__ Wv, const float* __restrict__ Wo,
    unsigned short* __restrict__ wt)
{
    __shared__ float tile[32][33];
    const int z = blockIdx.z;
    const float* W = (z == 0) ? Wq : (z == 1) ? Wk : (z == 2) ? Wv : Wo;
    const int k0 = blockIdx.x * 32, n0 = blockIdx.y * 32;
    const int t = threadIdx.x;
    const int r = t >> 3, c4 = (t & 7) * 4;

    float4 v = *(const float4*)(W + (size_t)(k0 + r) * D + n0 + c4);
    tile[r][c4 + 0] = v.x; tile[r][c4 + 1] = v.y;
    tile[r][c4 + 2] = v.z; tile[r][c4 + 3] = v.w;
    __syncthreads();
    ushort4 o = make_ushort4(f2bf(tile[c4 + 0][r]), f2bf(tile[c4 + 1][r]),
                             f2bf(tile[c4 + 2][r]), f2bf(tile[c4 + 3][r]));
    *(ushort4*)(wt + ((size_t)z * D + n0 + r) * D + k0 + c4) = o;
}

// ---------------------------------------------------------------------------
// QKV GEMM, bf16 MFMA. A = xb [8192][768], B = wt[z][n][k] (z = n0/768).
// 128x128 tile, BK=64, global_load_lds staging with XOR-8 swizzle.
// Q is pre-scaled by 0.125*log2(e) so attention softmax can use exp2.
// Epilogue: direct stores (WRITE_SIZE already exact -- L2 combines the
// nt-unrolled row segments; v17's LDS-transpose was neutral).
// grid (64, 18).
// ---------------------------------------------------------------------------
__global__ __launch_bounds__(256) void gemm_qkv(
    const unsigned short* __restrict__ xb,
    const unsigned short* __restrict__ wt,
    unsigned short* __restrict__ qb, unsigned short* __restrict__ kb,
    unsigned short* __restrict__ vtb)
{
    __shared__ unsigned short As[128 * 64];
    __shared__ unsigned short Bs[128 * 64];

    const int t = threadIdx.x;
    const int lane = t & 63, w = t >> 6;
    const int l16 = lane & 15, quad = lane >> 4;
    const int wm = w & 1, wn = w >> 1;
    const int m0 = blockIdx.x * 128;
    const int n0g = blockIdx.y * 128;
    const int z = n0g / 768;
    const int c0 = n0g - z * 768;
    const unsigned short* Wz = wt + (size_t)z * D * D;

    f32x4 acc[4][4] = {};

    for (int k0 = 0; k0 < D; k0 += 64) {
#pragma unroll
        for (int i = 0; i < 4; ++i) {
            int g = i * 256 + w * 64 + lane;
            int row = g >> 3, cl = g & 7, cg = cl ^ (row & 7);
            GLDS16(xb + (size_t)(m0 + row) * D + k0 + cg * 8,
                   As + (size_t)(i * 256 + w * 64) * 8);
            GLDS16(Wz + (size_t)(c0 + row) * D + k0 + cg * 8,
                   Bs + (size_t)(i * 256 + w * 64) * 8);
        }
        __syncthreads();
#pragma unroll
        for (int kk = 0; kk < 2; ++kk) {
            bf16x8 af[4], bf_[4];
#pragma unroll
            for (int mt = 0; mt < 4; ++mt) {
                int r = wm * 64 + mt * 16 + l16;
                int c = kk * 4 + quad;
                af[mt] = *(const bf16x8*)&As[(r * 8 + (c ^ (r & 7))) * 8];
            }
#pragma unroll
            for (int nt = 0; nt < 4; ++nt) {
                int r = wn * 64 + nt * 16 + l16;
                int c = kk * 4 + quad;
                bf_[nt] = *(const bf16x8*)&Bs[(r * 8 + (c ^ (r & 7))) * 8];
            }
#pragma unroll
            for (int mt = 0; mt < 4; ++mt)
#pragma unroll
                for (int nt = 0; nt < 4; ++nt)
                    acc[mt][nt] = __builtin_amdgcn_mfma_f32_16x16x32_bf16(
                        af[mt], bf_[nt], acc[mt][nt], 0, 0, 0);
        }
        __syncthreads();
    }

    if (z < 2) {
        unsigned short* outp = (z == 0) ? qb : kb;
        const float scale = (z == 0) ? 0.18033688011112042f : 1.0f; // .125*log2e
#pragma unroll
        for (int mt = 0; mt < 4; ++mt) {
#pragma unroll
            for (int reg = 0; reg < 4; ++reg) {
                int m = wm * 64 + mt * 16 + quad * 4 + reg;
                int ng = m0 + m;
                int b = ng >> 12, s = ng & 4095;
#pragma unroll
                for (int nt = 0; nt < 4; ++nt) {
                    int n = c0 + wn * 64 + nt * 16 + l16;
                    int h = n >> 6, dh = n & 63;
                    outp[(((size_t)b * NH + h) * S + s) * DH + dh] =
                        f2bf(acc[mt][nt][reg] * scale);
                }
            }
        }
    } else {
#pragma unroll
        for (int mt = 0; mt < 4; ++mt) {
#pragma unroll
            for (int nt = 0; nt < 4; ++nt) {
                int m = wm * 64 + mt * 16 + quad * 4;
                int ng = m0 + m;
                int b = ng >> 12, s = ng & 4095;
                int n = c0 + wn * 64 + nt * 16 + l16;
                int h = n >> 6, dh = n & 63;
                ushort4 p = make_ushort4(
                    f2bf(acc[mt][nt][0]), f2bf(acc[mt][nt][1]),
                    f2bf(acc[mt][nt][2]), f2bf(acc[mt][nt][3]));
                *(ushort4*)(vtb + (((size_t)b * NH + h) * DH + dh) * S + s) = p;
            }
        }
    }
}

// ---------------------------------------------------------------------------
// Flash attention v12 (verified best, ~85-88us): 8 waves x 16 q-rows,
// fixed-max softmax, in-register P (cvt_pk+permlane), ones-MFMA row sums,
// setprio, XOR-8 swizzle, dbuf K/V global_load_lds prefetch-after-barrier,
// grid 512, LPT queue. Plateau confirmed over 7 attack vectors:
// v9/v11/v13 (manual scheduling: corruption/spill/crash), v14 (KVBLK=128:
// V-tile bank conflicts), v15 (5 blocks/CU split: 2x barriers+staging),
// v16 (T14 reg-staging: TLP already covers), v19 (split-K: partial-traffic
// cost > makespan gain).
// ---------------------------------------------------------------------------
__global__ __launch_bounds__(512, 4) void attn_mfma(
    const unsigned short* __restrict__ qg,
    const unsigned short* __restrict__ kg,
    const unsigned short* __restrict__ vtg,
    unsigned short* __restrict__ ctxb,
    int* __restrict__ work_ctr)
{
    __shared__ unsigned short Ks[2][64 * 64];  // [key][dh], XOR-8 swizzle
    __shared__ unsigned short Vs[2][64 * 64];  // [dh][key], XOR-8 swizzle
    __shared__ int s_item;

    const float INF = __builtin_inff();
    const int t = threadIdx.x;
    const int w = t >> 6, lane = t & 63;
    const int l16 = lane & 15, quad = lane >> 4;
    const int a7 = l16 & 7;
    // staging: 512 threads cover 64 rows x 8 col-segments in one GLDS16
    const int srow = t >> 3;
    const int scg = (t & 7) ^ (srow & 7);

    bf16x8 vone;
#pragma unroll
    for (int i = 0; i < 8; ++i) vone[i] = (short)0x3F80;   // bf16 1.0

    for (;;) {
        if (t == 0) s_item = atomicAdd(work_ctr, 1);
        __syncthreads();                 // broadcast item; prior LDS reads done
        const int p = s_item;
        if (p >= N_ITEMS) return;        // uniform exit

        const int qt = 31 - (p / (NH * BATCH));   // longest first
        const int hb = p % (NH * BATCH);
        const int h = hb % NH, b = hb / NH;
        const size_t hbase = ((size_t)b * NH + h) * (size_t)S * DH;
        const unsigned short* kp = kg + hbase;
        const unsigned short* vp = vtg + hbase;

        // this wave's 16 q-rows; Q^T B-fragments (reused across all tiles)
        const int qrow = qt * 128 + w * 16 + l16;
        bf16x8 bq[2];
#pragma unroll
        for (int kk = 0; kk < 2; ++kk)
            bq[kk] = *(const bf16x8*)(qg + hbase + (size_t)qrow * DH +
                                      kk * 32 + quad * 8);

        f32x4 acc_o[4] = {};             // O^T: row = dh-local, col = qrow = l16
        f32x4 acc_sum = {};              // row sums via ones-MFMA (replicated)

        const int jmax = 2 * qt + 1, jd = 2 * qt;

        // preload tile 0 into buffer 0 (one GLDS16 per array per thread)
        GLDS16(kp + (size_t)srow * DH + scg * 8, &Ks[0][(size_t)w * 64 * 8]);
        GLDS16(vp + (size_t)srow * S + scg * 8, &Vs[0][(size_t)w * 64 * 8]);

        for (int j = 0; j <= jmax; ++j) {
            const int cur = j & 1;
            __syncthreads();             // drains tile-j loads; buf cur^1 free
            if (j < jmax) {              // prefetch j+1, overlaps compute
                GLDS16(kp + (size_t)((j + 1) * 64 + srow) * DH + scg * 8,
                       &Ks[cur ^ 1][(size_t)w * 64 * 8]);
                GLDS16(vp + (size_t)srow * S + (j + 1) * 64 + scg * 8,
                       &Vs[cur ^ 1][(size_t)w * 64 * 8]);
            }

            const unsigned short* Kc = Ks[cur];
            const unsigned short* Vc = Vs[cur];

            // --- S^T = K Q^T (one 16-row strip) ---
            f32x4 acc_s[4] = {};
            __builtin_amdgcn_s_setprio(1);
#pragma unroll
            for (int kk = 0; kk < 2; ++kk)
#pragma unroll
                for (int ms = 0; ms < 4; ++ms) {
                    int r = ms * 16 + l16, c = kk * 4 + quad;
                    bf16x8 ak = *(const bf16x8*)&Kc[(r * 8 + (c ^ a7)) * 8];
                    acc_s[ms] = __builtin_amdgcn_mfma_f32_16x16x32_bf16(
                        ak, bq[kk], acc_s[ms], 0, 0, 0);
                }
            __builtin_amdgcn_s_setprio(0);

            // --- causal mask: only the 2 diagonal tiles (uniform branch) ---
            if (j >= jd) {
#pragma unroll
                for (int ms = 0; ms < 4; ++ms)
#pragma unroll
                    for (int reg = 0; reg < 4; ++reg)
                        if ((j * 64 + ms * 16 + quad * 4 + reg) > qrow)
                            acc_s[ms][reg] = -INF;   // exp2 -> 0
            }

            // --- fixed-max softmax: P = exp2(S); pack + permlane -> bp ---
            bf16x8 bp[2];
            {
                unsigned ulo[4], uhi[4];
#pragma unroll
                for (int ms = 0; ms < 4; ++ms) {
                    float e0 = fexp2(acc_s[ms][0]);
                    float e1 = fexp2(acc_s[ms][1]);
                    float e2 = fexp2(acc_s[ms][2]);
                    float e3 = fexp2(acc_s[ms][3]);
                    asm("v_cvt_pk_bf16_f32 %0, %1, %2"
                        : "=v"(ulo[ms]) : "v"(e0), "v"(e1));
                    asm("v_cvt_pk_bf16_f32 %0, %1, %2"
                        : "=v"(uhi[ms]) : "v"(e2), "v"(e3));
                }
#pragma unroll
                for (int kp2 = 0; kp2 < 2; ++kp2) {
                    uint32x2 lo = __builtin_amdgcn_permlane32_swap(
                        ulo[2 * kp2], ulo[2 * kp2 + 1], false, false);
                    uint32x2 s02 = __builtin_amdgcn_permlane16_swap(
                        lo[0], lo[1], false, false);
                    uint32x2 hi = __builtin_amdgcn_permlane32_swap(
                        uhi[2 * kp2], uhi[2 * kp2 + 1], false, false);
                    uint32x2 s13 = __builtin_amdgcn_permlane16_swap(
                        hi[0], hi[1], false, false);
                    union { unsigned u[4]; bf16x8 v; } pb;
                    pb.u[0] = s02[0]; pb.u[1] = s13[0];
                    pb.u[2] = s02[1]; pb.u[3] = s13[1];
                    bp[kp2] = pb.v;
                }
            }

            // --- O^T += V^T P^T; row sums via ones-MFMA ---
            __builtin_amdgcn_s_setprio(1);
#pragma unroll
            for (int kk = 0; kk < 2; ++kk) {
#pragma unroll
                for (int d = 0; d < 4; ++d) {
                    int r = d * 16 + l16, c = kk * 4 + quad;
                    bf16x8 av = *(const bf16x8*)&Vc[(r * 8 + (c ^ a7)) * 8];
                    acc_o[d] = __builtin_amdgcn_mfma_f32_16x16x32_bf16(
                        av, bp[kk], acc_o[d], 0, 0, 0);
                }
                acc_sum = __builtin_amdgcn_mfma_f32_16x16x32_bf16(
                    vone, bp[kk], acc_sum, 0, 0, 0);
            }
            __builtin_amdgcn_s_setprio(0);
        }

        // --- epilogue: inv from replicated row sum; write O^T ---
        {
            float inv = 1.f / acc_sum[0];
            size_t base = ((size_t)(b * S + qrow)) * D + h * 64;
#pragma unroll
            for (int d = 0; d < 4; ++d) {
                ushort4 o;
                o.x = f2bf(acc_o[d][0] * inv);
                o.y = f2bf(acc_o[d][1] * inv);
                o.z = f2bf(acc_o[d][2] * inv);
                o.w = f2bf(acc_o[d][3] * inv);
                *(ushort4*)(ctxb + base + d * 16 + quad * 4) = o;
            }
        }
    }
}

// ---------------------------------------------------------------------------
// Output projection, bf16 MFMA. A = ctxb [8192][768], B = wt[3] (Wo^T),
// +bias, fp32 out. 128x64 tiles -> grid (64,12) = 768 blocks = 3/CU even
// (384 was 1.5/CU: half the CUs idled for the 2nd half of the kernel).
// LDS 24KB; ctxb refetch is L2/L3-resident.
// ---------------------------------------------------------------------------
__global__ __launch_bounds__(256) void gemm_out(
    const unsigned short* __restrict__ ctxb,
    const unsigned short* __restrict__ wt,
    const float* __restrict__ bo,
    float* __restrict__ out)
{
    __shared__ unsigned short As[128 * 64];   // 16 KB
    __shared__ unsigned short Bs[64 * 64];    // 8 KB

    const int t = threadIdx.x;
    const int lane = t & 63, w = t >> 6;
    const int l16 = lane & 15, quad = lane >> 4;
    const int m0 = blockIdx.x * 128;
    const int n0 = blockIdx.y * 64;
    const unsigned short* Wz = wt + (size_t)3 * D * D;

    f32x4 acc[2][4] = {};

    for (int k0 = 0; k0 < D; k0 += 64) {
#pragma unroll
        for (int i = 0; i < 4; ++i) {
            int g = i * 256 + w * 64 + lane;
            int row = g >> 3, cl = g & 7, cg = cl ^ (row & 7);
            GLDS16(ctxb + (size_t)(m0 + row) * D + k0 + cg * 8,
                   As + (size_t)(i * 256 + w * 64) * 8);
            if (i < 2)
                GLDS16(Wz + (size_t)(n0 + row) * D + k0 + cg * 8,
                       Bs + (size_t)(i * 256 + w * 64) * 8);
        }
        __syncthreads();
#pragma unroll
        for (int kk = 0; kk < 2; ++kk) {
            bf16x8 af[2], bf_[4];
#pragma unroll
            for (int mt = 0; mt < 2; ++mt) {
                int r = w * 32 + mt * 16 + l16;
                int c = kk * 4 + quad;
                af[mt] = *(const bf16x8*)&As[(r * 8 + (c ^ (r & 7))) * 8];
            }
#pragma unroll
            for (int nt = 0; nt < 4; ++nt) {
                int r = nt * 16 + l16;
                int c = kk * 4 + quad;
                bf_[nt] = *(const bf16x8*)&Bs[(r * 8 + (c ^ (r & 7))) * 8];
            }
#pragma unroll
            for (int mt = 0; mt < 2; ++mt)
#pragma unroll
                for (int nt = 0; nt < 4; ++nt)
                    acc[mt][nt] = __builtin_amdgcn_mfma_f32_16x16x32_bf16(
                        af[mt], bf_[nt], acc[mt][nt], 0, 0, 0);
        }
        __syncthreads();
    }

    float bv[4];
#pragma unroll
    for (int nt = 0; nt < 4; ++nt)
        bv[nt] = bo[n0 + nt * 16 + l16];
#pragma unroll
    for (int mt = 0; mt < 2; ++mt)
#pragma unroll
        for (int reg = 0; reg < 4; ++reg) {
            int m = m0 + w * 32 + mt * 16 + quad * 4 + reg;
#pragma unroll
            for (int nt = 0; nt < 4; ++nt)
                out[(size_t)m * D + n0 + nt * 16 + l16] =
                    acc[mt][nt][reg] + bv[nt];
        }
}

extern "C" void kernel_launch(void* const* d_in, const int* in_sizes, int n_in,
                              void* d_out, int out_size, void* d_ws, size_t ws_size,
                              hipStream_t stream)
{
    const float* x  = (const float*)d_in[0];
    const float* Wq = (const float*)d_in[1];
    const float* Wk = (const float*)d_in[2];
    const float* Wv = (const float*)d_in[3];
    const float* Wo = (const float*)d_in[4];
    const float* bo = (const float*)d_in[5];
    float* out = (float*)d_out;

    const size_t elems = (size_t)NROWS * D;     // 6,291,456
    unsigned short* xb   = (unsigned short*)d_ws;
    unsigned short* wt   = xb + elems;          // 4 * 768 * 768
    unsigned short* q    = wt + (size_t)4 * D * D;
    unsigned short* k    = q + elems;
    unsigned short* vt   = k + elems;
    unsigned short* ctxb = vt + elems;          // ends at byte 67,633,152
    int* work_ctr = (int*)((char*)d_ws + CTR_OFF);

    hipMemsetAsync(work_ctr, 0, sizeof(int), stream);

    cvt_x<<<NROWS * D / 1024, 256, 0, stream>>>(x, xb);
    dim3 gw(D / 32, D / 32, 4);
    cvt_w<<<gw, 256, 0, stream>>>(Wq, Wk, Wv, Wo, wt);

    dim3 g1(NROWS / 128, (3 * D) / 128);
    gemm_qkv<<<g1, 256, 0, stream>>>(xb, wt, q, k, vt);

    attn_mfma<<<512, 512, 0, stream>>>(q, k, vt, ctxb, work_ctr);

    dim3 g3(NROWS / 128, D / 64);
    gemm_out<<<g3, 256, 0, stream>>>(ctxb, wt, bo, out);
}

// Round 15
// 226.245 us; speedup vs baseline: 1.0603x; 1.0283x over previous
//
#include <hip/hip_runtime.h>

#define S 4096
#define BATCH 2
#define D 768
#define NH 12
#define DH 64
#define NROWS (BATCH * S)
#define N_ITEMS (32 * NH * BATCH)          // 768 (qt, h, b) work items
#define CTR_OFF 67633152                   // byte offset of queue counter in ws
#define NB_X 6144                          // cvt_in: blocks doing x->bf16
#define NB_W 2304                          // cvt_in: blocks doing W transpose

typedef __attribute__((ext_vector_type(8))) short bf16x8;   // 8 bf16 (4 VGPRs)
typedef __attribute__((ext_vector_type(4))) float f32x4;
typedef __attribute__((ext_vector_type(2))) unsigned uint32x2;

__device__ __forceinline__ unsigned short f2bf(float f) {
    unsigned u = __builtin_bit_cast(unsigned, f);
    u += 0x7fff + ((u >> 16) & 1);          // round-to-nearest-even
    return (unsigned short)(u >> 16);
}

__device__ __forceinline__ float fexp2(float x) {
#if __has_builtin(__builtin_amdgcn_exp2f)
    return __builtin_amdgcn_exp2f(x);       // raw v_exp_f32
#else
    return exp2f(x);
#endif
}

// async global->LDS, 16B per lane; lds ptr must be wave-uniform
#define GLDS16(g, l)                                                   \
    __builtin_amdgcn_global_load_lds(                                  \
        (const __attribute__((address_space(1))) void*)(g),            \
        (__attribute__((address_space(3))) void*)(l), 16, 0, 0)

// ---------------------------------------------------------------------------
// Fused input conversion (one dispatch, was cvt_x + cvt_w + memset):
//  blocks [0,6144):      x (fp32 [8192][768]) -> xb bf16 (1024 elems/block)
//  blocks [6144,8448):   W[k][n] fp32 -> wt[z][n][k] bf16, 32x32 LDS tile
//  block 0 thread 0 also zeroes the attn work queue counter (stream order
//  guarantees visibility before attn_mfma launches).
// Branch is block-uniform; 4.2KB LDS doesn't limit the x-path occupancy.
// ---------------------------------------------------------------------------
__global__ __launch_bounds__(256) void cvt_in(
    const float* __restrict__ x, unsigned short* __restrict__ xb,
    const float* __restrict__ Wq, const float* __restrict__ Wk,
    const float* __restrict__ Wv, const float* __restrict__ Wo,
    unsigned short* __restrict__ wt, int* __restrict__ work_ctr)
{
    __shared__ float tile[32][33];
    const int t = threadIdx.x;

    if (blockIdx.x < NB_X) {
        if (blockIdx.x == 0 && t == 0) *work_ctr = 0;
        int i = ((int)blockIdx.x * 256 + t) * 4;
        float4 v = *(const float4*)(x + i);
        ushort4 o = make_ushort4(f2bf(v.x), f2bf(v.y), f2bf(v.z), f2bf(v.w));
        *(ushort4*)(xb + i) = o;
    } else {
        int bid = blockIdx.x - NB_X;           // 0..2303
        int z = bid / 576;                     // 24x24 tiles per matrix
        int r2 = bid % 576;
        int k0 = (r2 / 24) * 32, n0 = (r2 % 24) * 32;
        const float* W = (z == 0) ? Wq : (z == 1) ? Wk : (z == 2) ? Wv : Wo;
        const int r = t >> 3, c4 = (t & 7) * 4;

        float4 v = *(const float4*)(W + (size_t)(k0 + r) * D + n0 + c4);
        tile[r][c4 + 0] = v.x; tile[r][c4 + 1] = v.y;
        tile[r][c4 + 2] = v.z; tile[r][c4 + 3] = v.w;
        __syncthreads();
        ushort4 o = make_ushort4(f2bf(tile[c4 + 0][r]), f2bf(tile[c4 + 1][r]),
                                 f2bf(tile[c4 + 2][r]), f2bf(tile[c4 + 3][r]));
        *(ushort4*)(wt + ((size_t)z * D + n0 + r) * D + k0 + c4) = o;
    }
}

// ---------------------------------------------------------------------------
// QKV GEMM, bf16 MFMA. A = xb [8192][768], B = wt[z][n][k] (z = n0/768).
// 128x128 tile, BK=64, global_load_lds staging with XOR-8 swizzle.
// Q is pre-scaled by 0.125*log2(e) so attention softmax can use exp2.
// Epilogue: direct stores (WRITE_SIZE already exact -- L2 combines the
// nt-unrolled row segments; v17's LDS-transpose was neutral).
// grid (64, 18).
// ---------------------------------------------------------------------------
__global__ __launch_bounds__(256) void gemm_qkv(
    const unsigned short* __restrict__ xb,
    const unsigned short* __restrict__ wt,
    unsigned short* __restrict__ qb, unsigned short* __restrict__ kb,
    unsigned short* __restrict__ vtb)
{
    __shared__ unsigned short As[128 * 64];
    __shared__ unsigned short Bs[128 * 64];

    const int t = threadIdx.x;
    const int lane = t & 63, w = t >> 6;
    const int l16 = lane & 15, quad = lane >> 4;
    const int wm = w & 1, wn = w >> 1;
    const int m0 = blockIdx.x * 128;
    const int n0g = blockIdx.y * 128;
    const int z = n0g / 768;
    const int c0 = n0g - z * 768;
    const unsigned short* Wz = wt + (size_t)z * D * D;

    f32x4 acc[4][4] = {};

    for (int k0 = 0; k0 < D; k0 += 64) {
#pragma unroll
        for (int i = 0; i < 4; ++i) {
            int g = i * 256 + w * 64 + lane;
            int row = g >> 3, cl = g & 7, cg = cl ^ (row & 7);
            GLDS16(xb + (size_t)(m0 + row) * D + k0 + cg * 8,
                   As + (size_t)(i * 256 + w * 64) * 8);
            GLDS16(Wz + (size_t)(c0 + row) * D + k0 + cg * 8,
                   Bs + (size_t)(i * 256 + w * 64) * 8);
        }
        __syncthreads();
#pragma unroll
        for (int kk = 0; kk < 2; ++kk) {
            bf16x8 af[4], bf_[4];
#pragma unroll
            for (int mt = 0; mt < 4; ++mt) {
                int r = wm * 64 + mt * 16 + l16;
                int c = kk * 4 + quad;
                af[mt] = *(const bf16x8*)&As[(r * 8 + (c ^ (r & 7))) * 8];
            }
#pragma unroll
            for (int nt = 0; nt < 4; ++nt) {
                int r = wn * 64 + nt * 16 + l16;
                int c = kk * 4 + quad;
                bf_[nt] = *(const bf16x8*)&Bs[(r * 8 + (c ^ (r & 7))) * 8];
            }
#pragma unroll
            for (int mt = 0; mt < 4; ++mt)
#pragma unroll
                for (int nt = 0; nt < 4; ++nt)
                    acc[mt][nt] = __builtin_amdgcn_mfma_f32_16x16x32_bf16(
                        af[mt], bf_[nt], acc[mt][nt], 0, 0, 0);
        }
        __syncthreads();
    }

    if (z < 2) {
        unsigned short* outp = (z == 0) ? qb : kb;
        const float scale = (z == 0) ? 0.18033688011112042f : 1.0f; // .125*log2e
#pragma unroll
        for (int mt = 0; mt < 4; ++mt) {
#pragma unroll
            for (int reg = 0; reg < 4; ++reg) {
                int m = wm * 64 + mt * 16 + quad * 4 + reg;
                int ng = m0 + m;
                int b = ng >> 12, s = ng & 4095;
#pragma unroll
                for (int nt = 0; nt < 4; ++nt) {
                    int n = c0 + wn * 64 + nt * 16 + l16;
                    int h = n >> 6, dh = n & 63;
                    outp[(((size_t)b * NH + h) * S + s) * DH + dh] =
                        f2bf(acc[mt][nt][reg] * scale);
                }
            }
        }
    } else {
#pragma unroll
        for (int mt = 0; mt < 4; ++mt) {
#pragma unroll
            for (int nt = 0; nt < 4; ++nt) {
                int m = wm * 64 + mt * 16 + quad * 4;
                int ng = m0 + m;
                int b = ng >> 12, s = ng & 4095;
                int n = c0 + wn * 64 + nt * 16 + l16;
                int h = n >> 6, dh = n & 63;
                ushort4 p = make_ushort4(
                    f2bf(acc[mt][nt][0]), f2bf(acc[mt][nt][1]),
                    f2bf(acc[mt][nt][2]), f2bf(acc[mt][nt][3]));
                *(ushort4*)(vtb + (((size_t)b * NH + h) * DH + dh) * S + s) = p;
            }
        }
    }
}

// ---------------------------------------------------------------------------
// Flash attention v12 (verified best): 8 waves x 16 q-rows, fixed-max
// softmax, in-register P (cvt_pk+permlane), ones-MFMA row sums, setprio,
// XOR-8 swizzle, dbuf K/V global_load_lds prefetch-after-barrier, grid 512,
// LPT queue. Plateau confirmed over 7 attack vectors: v9/v11/v13 (manual
// scheduling: corruption/spill/crash), v14 (KVBLK=128: V-tile bank
// conflicts), v15 (5 blocks/CU split: 2x barriers+staging), v16 (T14
// reg-staging: TLP already covers), v19 (split-K: partial-traffic cost >
// makespan gain).
// ---------------------------------------------------------------------------
__global__ __launch_bounds__(512, 4) void attn_mfma(
    const unsigned short* __restrict__ qg,
    const unsigned short* __restrict__ kg,
    const unsigned short* __restrict__ vtg,
    unsigned short* __restrict__ ctxb,
    int* __restrict__ work_ctr)
{
    __shared__ unsigned short Ks[2][64 * 64];  // [key][dh], XOR-8 swizzle
    __shared__ unsigned short Vs[2][64 * 64];  // [dh][key], XOR-8 swizzle
    __shared__ int s_item;

    const float INF = __builtin_inff();
    const int t = threadIdx.x;
    const int w = t >> 6, lane = t & 63;
    const int l16 = lane & 15, quad = lane >> 4;
    const int a7 = l16 & 7;
    // staging: 512 threads cover 64 rows x 8 col-segments in one GLDS16
    const int srow = t >> 3;
    const int scg = (t & 7) ^ (srow & 7);

    bf16x8 vone;
#pragma unroll
    for (int i = 0; i < 8; ++i) vone[i] = (short)0x3F80;   // bf16 1.0

    for (;;) {
        if (t == 0) s_item = atomicAdd(work_ctr, 1);
        __syncthreads();                 // broadcast item; prior LDS reads done
        const int p = s_item;
        if (p >= N_ITEMS) return;        // uniform exit

        const int qt = 31 - (p / (NH * BATCH));   // longest first
        const int hb = p % (NH * BATCH);
        const int h = hb % NH, b = hb / NH;
        const size_t hbase = ((size_t)b * NH + h) * (size_t)S * DH;
        const unsigned short* kp = kg + hbase;
        const unsigned short* vp = vtg + hbase;

        // this wave's 16 q-rows; Q^T B-fragments (reused across all tiles)
        const int qrow = qt * 128 + w * 16 + l16;
        bf16x8 bq[2];
#pragma unroll
        for (int kk = 0; kk < 2; ++kk)
            bq[kk] = *(const bf16x8*)(qg + hbase + (size_t)qrow * DH +
                                      kk * 32 + quad * 8);

        f32x4 acc_o[4] = {};             // O^T: row = dh-local, col = qrow = l16
        f32x4 acc_sum = {};              // row sums via ones-MFMA (replicated)

        const int jmax = 2 * qt + 1, jd = 2 * qt;

        // preload tile 0 into buffer 0 (one GLDS16 per array per thread)
        GLDS16(kp + (size_t)srow * DH + scg * 8, &Ks[0][(size_t)w * 64 * 8]);
        GLDS16(vp + (size_t)srow * S + scg * 8, &Vs[0][(size_t)w * 64 * 8]);

        for (int j = 0; j <= jmax; ++j) {
            const int cur = j & 1;
            __syncthreads();             // drains tile-j loads; buf cur^1 free
            if (j < jmax) {              // prefetch j+1, overlaps compute
                GLDS16(kp + (size_t)((j + 1) * 64 + srow) * DH + scg * 8,
                       &Ks[cur ^ 1][(size_t)w * 64 * 8]);
                GLDS16(vp + (size_t)srow * S + (j + 1) * 64 + scg * 8,
                       &Vs[cur ^ 1][(size_t)w * 64 * 8]);
            }

            const unsigned short* Kc = Ks[cur];
            const unsigned short* Vc = Vs[cur];

            // --- S^T = K Q^T (one 16-row strip) ---
            f32x4 acc_s[4] = {};
            __builtin_amdgcn_s_setprio(1);
#pragma unroll
            for (int kk = 0; kk < 2; ++kk)
#pragma unroll
                for (int ms = 0; ms < 4; ++ms) {
                    int r = ms * 16 + l16, c = kk * 4 + quad;
                    bf16x8 ak = *(const bf16x8*)&Kc[(r * 8 + (c ^ a7)) * 8];
                    acc_s[ms] = __builtin_amdgcn_mfma_f32_16x16x32_bf16(
                        ak, bq[kk], acc_s[ms], 0, 0, 0);
                }
            __builtin_amdgcn_s_setprio(0);

            // --- causal mask: only the 2 diagonal tiles (uniform branch) ---
            if (j >= jd) {
#pragma unroll
                for (int ms = 0; ms < 4; ++ms)
#pragma unroll
                    for (int reg = 0; reg < 4; ++reg)
                        if ((j * 64 + ms * 16 + quad * 4 + reg) > qrow)
                            acc_s[ms][reg] = -INF;   // exp2 -> 0
            }

            // --- fixed-max softmax: P = exp2(S); pack + permlane -> bp ---
            bf16x8 bp[2];
            {
                unsigned ulo[4], uhi[4];
#pragma unroll
                for (int ms = 0; ms < 4; ++ms) {
                    float e0 = fexp2(acc_s[ms][0]);
                    float e1 = fexp2(acc_s[ms][1]);
                    float e2 = fexp2(acc_s[ms][2]);
                    float e3 = fexp2(acc_s[ms][3]);
                    asm("v_cvt_pk_bf16_f32 %0, %1, %2"
                        : "=v"(ulo[ms]) : "v"(e0), "v"(e1));
                    asm("v_cvt_pk_bf16_f32 %0, %1, %2"
                        : "=v"(uhi[ms]) : "v"(e2), "v"(e3));
                }
#pragma unroll
                for (int kp2 = 0; kp2 < 2; ++kp2) {
                    uint32x2 lo = __builtin_amdgcn_permlane32_swap(
                        ulo[2 * kp2], ulo[2 * kp2 + 1], false, false);
                    uint32x2 s02 = __builtin_amdgcn_permlane16_swap(
                        lo[0], lo[1], false, false);
                    uint32x2 hi = __builtin_amdgcn_permlane32_swap(
                        uhi[2 * kp2], uhi[2 * kp2 + 1], false, false);
                    uint32x2 s13 = __builtin_amdgcn_permlane16_swap(
                        hi[0], hi[1], false, false);
                    union { unsigned u[4]; bf16x8 v; } pb;
                    pb.u[0] = s02[0]; pb.u[1] = s13[0];
                    pb.u[2] = s02[1]; pb.u[3] = s13[1];
                    bp[kp2] = pb.v;
                }
            }

            // --- O^T += V^T P^T; row sums via ones-MFMA ---
            __builtin_amdgcn_s_setprio(1);
#pragma unroll
            for (int kk = 0; kk < 2; ++kk) {
#pragma unroll
                for (int d = 0; d < 4; ++d) {
                    int r = d * 16 + l16, c = kk * 4 + quad;
                    bf16x8 av = *(const bf16x8*)&Vc[(r * 8 + (c ^ a7)) * 8];
                    acc_o[d] = __builtin_amdgcn_mfma_f32_16x16x32_bf16(
                        av, bp[kk], acc_o[d], 0, 0, 0);
                }
                acc_sum = __builtin_amdgcn_mfma_f32_16x16x32_bf16(
                    vone, bp[kk], acc_sum, 0, 0, 0);
            }
            __builtin_amdgcn_s_setprio(0);
        }

        // --- epilogue: inv from replicated row sum; write O^T ---
        {
            float inv = 1.f / acc_sum[0];
            size_t base = ((size_t)(b * S + qrow)) * D + h * 64;
#pragma unroll
            for (int d = 0; d < 4; ++d) {
                ushort4 o;
                o.x = f2bf(acc_o[d][0] * inv);
                o.y = f2bf(acc_o[d][1] * inv);
                o.z = f2bf(acc_o[d][2] * inv);
                o.w = f2bf(acc_o[d][3] * inv);
                *(ushort4*)(ctxb + base + d * 16 + quad * 4) = o;
            }
        }
    }
}

// ---------------------------------------------------------------------------
// Output projection, bf16 MFMA. A = ctxb [8192][768], B = wt[3] (Wo^T),
// +bias, fp32 out. 128x64 tiles -> grid (64,12) = 768 blocks = 3/CU even
// (384 was 1.5/CU: half the CUs idled for the 2nd half of the kernel).
// LDS 24KB; ctxb refetch is L2/L3-resident.
// ---------------------------------------------------------------------------
__global__ __launch_bounds__(256) void gemm_out(
    const unsigned short* __restrict__ ctxb,
    const unsigned short* __restrict__ wt,
    const float* __restrict__ bo,
    float* __restrict__ out)
{
    __shared__ unsigned short As[128 * 64];   // 16 KB
    __shared__ unsigned short Bs[64 * 64];    // 8 KB

    const int t = threadIdx.x;
    const int lane = t & 63, w = t >> 6;
    const int l16 = lane & 15, quad = lane >> 4;
    const int m0 = blockIdx.x * 128;
    const int n0 = blockIdx.y * 64;
    const unsigned short* Wz = wt + (size_t)3 * D * D;

    f32x4 acc[2][4] = {};

    for (int k0 = 0; k0 < D; k0 += 64) {
#pragma unroll
        for (int i = 0; i < 4; ++i) {
            int g = i * 256 + w * 64 + lane;
            int row = g >> 3, cl = g & 7, cg = cl ^ (row & 7);
            GLDS16(ctxb + (size_t)(m0 + row) * D + k0 + cg * 8,
                   As + (size_t)(i * 256 + w * 64) * 8);
            if (i < 2)
                GLDS16(Wz + (size_t)(n0 + row) * D + k0 + cg * 8,
                       Bs + (size_t)(i * 256 + w * 64) * 8);
        }
        __syncthreads();
#pragma unroll
        for (int kk = 0; kk < 2; ++kk) {
            bf16x8 af[2], bf_[4];
#pragma unroll
            for (int mt = 0; mt < 2; ++mt) {
                int r = w * 32 + mt * 16 + l16;
                int c = kk * 4 + quad;
                af[mt] = *(const bf16x8*)&As[(r * 8 + (c ^ (r & 7))) * 8];
            }
#pragma unroll
            for (int nt = 0; nt < 4; ++nt) {
                int r = nt * 16 + l16;
                int c = kk * 4 + quad;
                bf_[nt] = *(const bf16x8*)&Bs[(r * 8 + (c ^ (r & 7))) * 8];
            }
#pragma unroll
            for (int mt = 0; mt < 2; ++mt)
#pragma unroll
                for (int nt = 0; nt < 4; ++nt)
                    acc[mt][nt] = __builtin_amdgcn_mfma_f32_16x16x32_bf16(
                        af[mt], bf_[nt], acc[mt][nt], 0, 0, 0);
        }
        __syncthreads();
    }

    float bv[4];
#pragma unroll
    for (int nt = 0; nt < 4; ++nt)
        bv[nt] = bo[n0 + nt * 16 + l16];
#pragma unroll
    for (int mt = 0; mt < 2; ++mt)
#pragma unroll
        for (int reg = 0; reg < 4; ++reg) {
            int m = m0 + w * 32 + mt * 16 + quad * 4 + reg;
#pragma unroll
            for (int nt = 0; nt < 4; ++nt)
                out[(size_t)m * D + n0 + nt * 16 + l16] =
                    acc[mt][nt][reg] + bv[nt];
        }
}

extern "C" void kernel_launch(void* const* d_in, const int* in_sizes, int n_in,
                              void* d_out, int out_size, void* d_ws, size_t ws_size,
                              hipStream_t stream)
{
    const float* x  = (const float*)d_in[0];
    const float* Wq = (const float*)d_in[1];
    const float* Wk = (const float*)d_in[2];
    const float* Wv = (const float*)d_in[3];
    const float* Wo = (const float*)d_in[4];
    const float* bo = (const float*)d_in[5];
    float* out = (float*)d_out;

    const size_t elems = (size_t)NROWS * D;     // 6,291,456
    unsigned short* xb   = (unsigned short*)d_ws;
    unsigned short* wt   = xb + elems;          // 4 * 768 * 768
    unsigned short* q    = wt + (size_t)4 * D * D;
    unsigned short* k    = q + elems;
    unsigned short* vt   = k + elems;
    unsigned short* ctxb = vt + elems;          // ends at byte 67,633,152
    int* work_ctr = (int*)((char*)d_ws + CTR_OFF);

    // one fused conversion dispatch (x->bf16, W->W^T bf16, ctr reset)
    cvt_in<<<NB_X + NB_W, 256, 0, stream>>>(x, xb, Wq, Wk, Wv, Wo, wt,
                                            work_ctr);

    dim3 g1(NROWS / 128, (3 * D) / 128);
    gemm_qkv<<<g1, 256, 0, stream>>>(xb, wt, q, k, vt);

    attn_mfma<<<512, 512, 0, stream>>>(q, k, vt, ctxb, work_ctr);

    dim3 g3(NROWS / 128, D / 64);
    gemm_out<<<g3, 256, 0, stream>>>(ctxb, wt, bo, out);
}

// Round 16
// 217.061 us; speedup vs baseline: 1.1052x; 1.0423x over previous
//
#include <hip/hip_runtime.h>

#define S 4096
#define BATCH 2
#define D 768
#define NH 12
#define DH 64
#define NROWS (BATCH * S)
#define N_ITEMS (32 * NH * BATCH)          // 768 (qt, h, b) work items
#define CTR_OFF 67633152                   // byte offset of queue counter in ws
#define NB_X 6144                          // cvt_in: blocks doing x->bf16
#define NB_W 2304                          // cvt_in: blocks doing W transpose

typedef __attribute__((ext_vector_type(8))) short bf16x8;   // 8 bf16 (4 VGPRs)
typedef __attribute__((ext_vector_type(4))) float f32x4;
typedef __attribute__((ext_vector_type(2))) unsigned uint32x2;

__device__ __forceinline__ unsigned short f2bf(float f) {
    unsigned u = __builtin_bit_cast(unsigned, f);
    u += 0x7fff + ((u >> 16) & 1);          // round-to-nearest-even
    return (unsigned short)(u >> 16);
}

__device__ __forceinline__ float fexp2(float x) {
#if __has_builtin(__builtin_amdgcn_exp2f)
    return __builtin_amdgcn_exp2f(x);       // raw v_exp_f32
#else
    return exp2f(x);
#endif
}

// async global->LDS, 16B per lane; lds ptr must be wave-uniform
#define GLDS16(g, l)                                                   \
    __builtin_amdgcn_global_load_lds(                                  \
        (const __attribute__((address_space(1))) void*)(g),            \
        (__attribute__((address_space(3))) void*)(l), 16, 0, 0)

// ---------------------------------------------------------------------------
// Fused input conversion (one dispatch, was cvt_x + cvt_w + memset):
//  blocks [0,6144):      x (fp32 [8192][768]) -> xb bf16 (1024 elems/block)
//  blocks [6144,8448):   W[k][n] fp32 -> wt[z][n][k] bf16, 32x32 LDS tile
//  block 0 thread 0 also zeroes the attn work queue counter (stream order
//  guarantees visibility before attn_mfma launches).
// ---------------------------------------------------------------------------
__global__ __launch_bounds__(256) void cvt_in(
    const float* __restrict__ x, unsigned short* __restrict__ xb,
    const float* __restrict__ Wq, const float* __restrict__ Wk,
    const float* __restrict__ Wv, const float* __restrict__ Wo,
    unsigned short* __restrict__ wt, int* __restrict__ work_ctr)
{
    __shared__ float tile[32][33];
    const int t = threadIdx.x;

    if (blockIdx.x < NB_X) {
        if (blockIdx.x == 0 && t == 0) *work_ctr = 0;
        int i = ((int)blockIdx.x * 256 + t) * 4;
        float4 v = *(const float4*)(x + i);
        ushort4 o = make_ushort4(f2bf(v.x), f2bf(v.y), f2bf(v.z), f2bf(v.w));
        *(ushort4*)(xb + i) = o;
    } else {
        int bid = blockIdx.x - NB_X;           // 0..2303
        int z = bid / 576;                     // 24x24 tiles per matrix
        int r2 = bid % 576;
        int k0 = (r2 / 24) * 32, n0 = (r2 % 24) * 32;
        const float* W = (z == 0) ? Wq : (z == 1) ? Wk : (z == 2) ? Wv : Wo;
        const int r = t >> 3, c4 = (t & 7) * 4;

        float4 v = *(const float4*)(W + (size_t)(k0 + r) * D + n0 + c4);
        tile[r][c4 + 0] = v.x; tile[r][c4 + 1] = v.y;
        tile[r][c4 + 2] = v.z; tile[r][c4 + 3] = v.w;
        __syncthreads();
        ushort4 o = make_ushort4(f2bf(tile[c4 + 0][r]), f2bf(tile[c4 + 1][r]),
                                 f2bf(tile[c4 + 2][r]), f2bf(tile[c4 + 3][r]));
        *(ushort4*)(wt + ((size_t)z * D + n0 + r) * D + k0 + c4) = o;
    }
}

// ---------------------------------------------------------------------------
// QKV GEMM, bf16 MFMA. A = xb [8192][768], B = wt[z][n][k] (z = n0/768).
// v21: 64x128 tile (was 128x128) -> grid (128,18) = 2304 blocks = 9/CU
// EVEN (1152 was 4.5/CU: 128 CUs ran a 5th tile while 128 idled, +11%
// makespan on the 2nd-largest kernel). Per-wave 32x64 sub-tile (wm*32,
// mt<2; wn*64, nt<4), acc[2][4]; same verified swizzle/layout algebra.
// B-panel refetch doubles (L2-resident, 3.5MB). LDS 24KB. BK=64,
// global_load_lds staging with XOR-8 swizzle. Q pre-scaled by
// 0.125*log2(e) so attention softmax can use exp2.
// ---------------------------------------------------------------------------
__global__ __launch_bounds__(256) void gemm_qkv(
    const unsigned short* __restrict__ xb,
    const unsigned short* __restrict__ wt,
    unsigned short* __restrict__ qb, unsigned short* __restrict__ kb,
    unsigned short* __restrict__ vtb)
{
    __shared__ unsigned short As[64 * 64];    // 8 KB
    __shared__ unsigned short Bs[128 * 64];   // 16 KB

    const int t = threadIdx.x;
    const int lane = t & 63, w = t >> 6;
    const int l16 = lane & 15, quad = lane >> 4;
    const int wm = w & 1, wn = w >> 1;
    const int m0 = blockIdx.x * 64;
    const int n0g = blockIdx.y * 128;
    const int z = n0g / 768;
    const int c0 = n0g - z * 768;
    const unsigned short* Wz = wt + (size_t)z * D * D;

    f32x4 acc[2][4] = {};

    for (int k0 = 0; k0 < D; k0 += 64) {
#pragma unroll
        for (int i = 0; i < 4; ++i) {
            int g = i * 256 + w * 64 + lane;
            int row = g >> 3, cl = g & 7, cg = cl ^ (row & 7);
            if (i < 2)
                GLDS16(xb + (size_t)(m0 + row) * D + k0 + cg * 8,
                       As + (size_t)(i * 256 + w * 64) * 8);
            GLDS16(Wz + (size_t)(c0 + row) * D + k0 + cg * 8,
                   Bs + (size_t)(i * 256 + w * 64) * 8);
        }
        __syncthreads();
#pragma unroll
        for (int kk = 0; kk < 2; ++kk) {
            bf16x8 af[2], bf_[4];
#pragma unroll
            for (int mt = 0; mt < 2; ++mt) {
                int r = wm * 32 + mt * 16 + l16;
                int c = kk * 4 + quad;
                af[mt] = *(const bf16x8*)&As[(r * 8 + (c ^ (r & 7))) * 8];
            }
#pragma unroll
            for (int nt = 0; nt < 4; ++nt) {
                int r = wn * 64 + nt * 16 + l16;
                int c = kk * 4 + quad;
                bf_[nt] = *(const bf16x8*)&Bs[(r * 8 + (c ^ (r & 7))) * 8];
            }
#pragma unroll
            for (int mt = 0; mt < 2; ++mt)
#pragma unroll
                for (int nt = 0; nt < 4; ++nt)
                    acc[mt][nt] = __builtin_amdgcn_mfma_f32_16x16x32_bf16(
                        af[mt], bf_[nt], acc[mt][nt], 0, 0, 0);
        }
        __syncthreads();
    }

    if (z < 2) {
        unsigned short* outp = (z == 0) ? qb : kb;
        const float scale = (z == 0) ? 0.18033688011112042f : 1.0f; // .125*log2e
#pragma unroll
        for (int mt = 0; mt < 2; ++mt) {
#pragma unroll
            for (int reg = 0; reg < 4; ++reg) {
                int m = wm * 32 + mt * 16 + quad * 4 + reg;
                int ng = m0 + m;
                int b = ng >> 12, s = ng & 4095;
#pragma unroll
                for (int nt = 0; nt < 4; ++nt) {
                    int n = c0 + wn * 64 + nt * 16 + l16;
                    int h = n >> 6, dh = n & 63;
                    outp[(((size_t)b * NH + h) * S + s) * DH + dh] =
                        f2bf(acc[mt][nt][reg] * scale);
                }
            }
        }
    } else {
#pragma unroll
        for (int mt = 0; mt < 2; ++mt) {
#pragma unroll
            for (int nt = 0; nt < 4; ++nt) {
                int m = wm * 32 + mt * 16 + quad * 4;
                int ng = m0 + m;
                int b = ng >> 12, s = ng & 4095;
                int n = c0 + wn * 64 + nt * 16 + l16;
                int h = n >> 6, dh = n & 63;
                ushort4 p = make_ushort4(
                    f2bf(acc[mt][nt][0]), f2bf(acc[mt][nt][1]),
                    f2bf(acc[mt][nt][2]), f2bf(acc[mt][nt][3]));
                *(ushort4*)(vtb + (((size_t)b * NH + h) * DH + dh) * S + s) = p;
            }
        }
    }
}

// ---------------------------------------------------------------------------
// Flash attention v12 (verified best): 8 waves x 16 q-rows, fixed-max
// softmax, in-register P (cvt_pk+permlane), ones-MFMA row sums, setprio,
// XOR-8 swizzle, dbuf K/V global_load_lds prefetch-after-barrier, grid 512,
// LPT queue. Plateau confirmed over 7 attack vectors.
// ---------------------------------------------------------------------------
__global__ __launch_bounds__(512, 4) void attn_mfma(
    const unsigned short* __restrict__ qg,
    const unsigned short* __restrict__ kg,
    const unsigned short* __restrict__ vtg,
    unsigned short* __restrict__ ctxb,
    int* __restrict__ work_ctr)
{
    __shared__ unsigned short Ks[2][64 * 64];  // [key][dh], XOR-8 swizzle
    __shared__ unsigned short Vs[2][64 * 64];  // [dh][key], XOR-8 swizzle
    __shared__ int s_item;

    const float INF = __builtin_inff();
    const int t = threadIdx.x;
    const int w = t >> 6, lane = t & 63;
    const int l16 = lane & 15, quad = lane >> 4;
    const int a7 = l16 & 7;
    // staging: 512 threads cover 64 rows x 8 col-segments in one GLDS16
    const int srow = t >> 3;
    const int scg = (t & 7) ^ (srow & 7);

    bf16x8 vone;
#pragma unroll
    for (int i = 0; i < 8; ++i) vone[i] = (short)0x3F80;   // bf16 1.0

    for (;;) {
        if (t == 0) s_item = atomicAdd(work_ctr, 1);
        __syncthreads();                 // broadcast item; prior LDS reads done
        const int p = s_item;
        if (p >= N_ITEMS) return;        // uniform exit

        const int qt = 31 - (p / (NH * BATCH));   // longest first
        const int hb = p % (NH * BATCH);
        const int h = hb % NH, b = hb / NH;
        const size_t hbase = ((size_t)b * NH + h) * (size_t)S * DH;
        const unsigned short* kp = kg + hbase;
        const unsigned short* vp = vtg + hbase;

        // this wave's 16 q-rows; Q^T B-fragments (reused across all tiles)
        const int qrow = qt * 128 + w * 16 + l16;
        bf16x8 bq[2];
#pragma unroll
        for (int kk = 0; kk < 2; ++kk)
            bq[kk] = *(const bf16x8*)(qg + hbase + (size_t)qrow * DH +
                                      kk * 32 + quad * 8);

        f32x4 acc_o[4] = {};             // O^T: row = dh-local, col = qrow = l16
        f32x4 acc_sum = {};              // row sums via ones-MFMA (replicated)

        const int jmax = 2 * qt + 1, jd = 2 * qt;

        // preload tile 0 into buffer 0 (one GLDS16 per array per thread)
        GLDS16(kp + (size_t)srow * DH + scg * 8, &Ks[0][(size_t)w * 64 * 8]);
        GLDS16(vp + (size_t)srow * S + scg * 8, &Vs[0][(size_t)w * 64 * 8]);

        for (int j = 0; j <= jmax; ++j) {
            const int cur = j & 1;
            __syncthreads();             // drains tile-j loads; buf cur^1 free
            if (j < jmax) {              // prefetch j+1, overlaps compute
                GLDS16(kp + (size_t)((j + 1) * 64 + srow) * DH + scg * 8,
                       &Ks[cur ^ 1][(size_t)w * 64 * 8]);
                GLDS16(vp + (size_t)srow * S + (j + 1) * 64 + scg * 8,
                       &Vs[cur ^ 1][(size_t)w * 64 * 8]);
            }

            const unsigned short* Kc = Ks[cur];
            const unsigned short* Vc = Vs[cur];

            // --- S^T = K Q^T (one 16-row strip) ---
            f32x4 acc_s[4] = {};
            __builtin_amdgcn_s_setprio(1);
#pragma unroll
            for (int kk = 0; kk < 2; ++kk)
#pragma unroll
                for (int ms = 0; ms < 4; ++ms) {
                    int r = ms * 16 + l16, c = kk * 4 + quad;
                    bf16x8 ak = *(const bf16x8*)&Kc[(r * 8 + (c ^ a7)) * 8];
                    acc_s[ms] = __builtin_amdgcn_mfma_f32_16x16x32_bf16(
                        ak, bq[kk], acc_s[ms], 0, 0, 0);
                }
            __builtin_amdgcn_s_setprio(0);

            // --- causal mask: only the 2 diagonal tiles (uniform branch) ---
            if (j >= jd) {
#pragma unroll
                for (int ms = 0; ms < 4; ++ms)
#pragma unroll
                    for (int reg = 0; reg < 4; ++reg)
                        if ((j * 64 + ms * 16 + quad * 4 + reg) > qrow)
                            acc_s[ms][reg] = -INF;   // exp2 -> 0
            }

            // --- fixed-max softmax: P = exp2(S); pack + permlane -> bp ---
            bf16x8 bp[2];
            {
                unsigned ulo[4], uhi[4];
#pragma unroll
                for (int ms = 0; ms < 4; ++ms) {
                    float e0 = fexp2(acc_s[ms][0]);
                    float e1 = fexp2(acc_s[ms][1]);
                    float e2 = fexp2(acc_s[ms][2]);
                    float e3 = fexp2(acc_s[ms][3]);
                    asm("v_cvt_pk_bf16_f32 %0, %1, %2"
                        : "=v"(ulo[ms]) : "v"(e0), "v"(e1));
                    asm("v_cvt_pk_bf16_f32 %0, %1, %2"
                        : "=v"(uhi[ms]) : "v"(e2), "v"(e3));
                }
#pragma unroll
                for (int kp2 = 0; kp2 < 2; ++kp2) {
                    uint32x2 lo = __builtin_amdgcn_permlane32_swap(
                        ulo[2 * kp2], ulo[2 * kp2 + 1], false, false);
                    uint32x2 s02 = __builtin_amdgcn_permlane16_swap(
                        lo[0], lo[1], false, false);
                    uint32x2 hi = __builtin_amdgcn_permlane32_swap(
                        uhi[2 * kp2], uhi[2 * kp2 + 1], false, false);
                    uint32x2 s13 = __builtin_amdgcn_permlane16_swap(
                        hi[0], hi[1], false, false);
                    union { unsigned u[4]; bf16x8 v; } pb;
                    pb.u[0] = s02[0]; pb.u[1] = s13[0];
                    pb.u[2] = s02[1]; pb.u[3] = s13[1];
                    bp[kp2] = pb.v;
                }
            }

            // --- O^T += V^T P^T; row sums via ones-MFMA ---
            __builtin_amdgcn_s_setprio(1);
#pragma unroll
            for (int kk = 0; kk < 2; ++kk) {
#pragma unroll
                for (int d = 0; d < 4; ++d) {
                    int r = d * 16 + l16, c = kk * 4 + quad;
                    bf16x8 av = *(const bf16x8*)&Vc[(r * 8 + (c ^ a7)) * 8];
                    acc_o[d] = __builtin_amdgcn_mfma_f32_16x16x32_bf16(
                        av, bp[kk], acc_o[d], 0, 0, 0);
                }
                acc_sum = __builtin_amdgcn_mfma_f32_16x16x32_bf16(
                    vone, bp[kk], acc_sum, 0, 0, 0);
            }
            __builtin_amdgcn_s_setprio(0);
        }

        // --- epilogue: inv from replicated row sum; write O^T ---
        {
            float inv = 1.f / acc_sum[0];
            size_t base = ((size_t)(b * S + qrow)) * D + h * 64;
#pragma unroll
            for (int d = 0; d < 4; ++d) {
                ushort4 o;
                o.x = f2bf(acc_o[d][0] * inv);
                o.y = f2bf(acc_o[d][1] * inv);
                o.z = f2bf(acc_o[d][2] * inv);
                o.w = f2bf(acc_o[d][3] * inv);
                *(ushort4*)(ctxb + base + d * 16 + quad * 4) = o;
            }
        }
    }
}

// ---------------------------------------------------------------------------
// Output projection, bf16 MFMA. A = ctxb [8192][768], B = wt[3] (Wo^T),
// +bias, fp32 out. 128x64 tiles -> grid (64,12) = 768 blocks = 3/CU even.
// LDS 24KB; ctxb refetch is L2/L3-resident.
// ---------------------------------------------------------------------------
__global__ __launch_bounds__(256) void gemm_out(
    const unsigned short* __restrict__ ctxb,
    const unsigned short* __restrict__ wt,
    const float* __restrict__ bo,
    float* __restrict__ out)
{
    __shared__ unsigned short As[128 * 64];   // 16 KB
    __shared__ unsigned short Bs[64 * 64];    // 8 KB

    const int t = threadIdx.x;
    const int lane = t & 63, w = t >> 6;
    const int l16 = lane & 15, quad = lane >> 4;
    const int m0 = blockIdx.x * 128;
    const int n0 = blockIdx.y * 64;
    const unsigned short* Wz = wt + (size_t)3 * D * D;

    f32x4 acc[2][4] = {};

    for (int k0 = 0; k0 < D; k0 += 64) {
#pragma unroll
        for (int i = 0; i < 4; ++i) {
            int g = i * 256 + w * 64 + lane;
            int row = g >> 3, cl = g & 7, cg = cl ^ (row & 7);
            GLDS16(ctxb + (size_t)(m0 + row) * D + k0 + cg * 8,
                   As + (size_t)(i * 256 + w * 64) * 8);
            if (i < 2)
                GLDS16(Wz + (size_t)(n0 + row) * D + k0 + cg * 8,
                       Bs + (size_t)(i * 256 + w * 64) * 8);
        }
        __syncthreads();
#pragma unroll
        for (int kk = 0; kk < 2; ++kk) {
            bf16x8 af[2], bf_[4];
#pragma unroll
            for (int mt = 0; mt < 2; ++mt) {
                int r = w * 32 + mt * 16 + l16;
                int c = kk * 4 + quad;
                af[mt] = *(const bf16x8*)&As[(r * 8 + (c ^ (r & 7))) * 8];
            }
#pragma unroll
            for (int nt = 0; nt < 4; ++nt) {
                int r = nt * 16 + l16;
                int c = kk * 4 + quad;
                bf_[nt] = *(const bf16x8*)&Bs[(r * 8 + (c ^ (r & 7))) * 8];
            }
#pragma unroll
            for (int mt = 0; mt < 2; ++mt)
#pragma unroll
                for (int nt = 0; nt < 4; ++nt)
                    acc[mt][nt] = __builtin_amdgcn_mfma_f32_16x16x32_bf16(
                        af[mt], bf_[nt], acc[mt][nt], 0, 0, 0);
        }
        __syncthreads();
    }

    float bv[4];
#pragma unroll
    for (int nt = 0; nt < 4; ++nt)
        bv[nt] = bo[n0 + nt * 16 + l16];
#pragma unroll
    for (int mt = 0; mt < 2; ++mt)
#pragma unroll
        for (int reg = 0; reg < 4; ++reg) {
            int m = m0 + w * 32 + mt * 16 + quad * 4 + reg;
#pragma unroll
            for (int nt = 0; nt < 4; ++nt)
                out[(size_t)m * D + n0 + nt * 16 + l16] =
                    acc[mt][nt][reg] + bv[nt];
        }
}

extern "C" void kernel_launch(void* const* d_in, const int* in_sizes, int n_in,
                              void* d_out, int out_size, void* d_ws, size_t ws_size,
                              hipStream_t stream)
{
    const float* x  = (const float*)d_in[0];
    const float* Wq = (const float*)d_in[1];
    const float* Wk = (const float*)d_in[2];
    const float* Wv = (const float*)d_in[3];
    const float* Wo = (const float*)d_in[4];
    const float* bo = (const float*)d_in[5];
    float* out = (float*)d_out;

    const size_t elems = (size_t)NROWS * D;     // 6,291,456
    unsigned short* xb   = (unsigned short*)d_ws;
    unsigned short* wt   = xb + elems;          // 4 * 768 * 768
    unsigned short* q    = wt + (size_t)4 * D * D;
    unsigned short* k    = q + elems;
    unsigned short* vt   = k + elems;
    unsigned short* ctxb = vt + elems;          // ends at byte 67,633,152
    int* work_ctr = (int*)((char*)d_ws + CTR_OFF);

    // one fused conversion dispatch (x->bf16, W->W^T bf16, ctr reset)
    cvt_in<<<NB_X + NB_W, 256, 0, stream>>>(x, xb, Wq, Wk, Wv, Wo, wt,
                                            work_ctr);

    dim3 g1(NROWS / 64, (3 * D) / 128);
    gemm_qkv<<<g1, 256, 0, stream>>>(xb, wt, q, k, vt);

    attn_mfma<<<512, 512, 0, stream>>>(q, k, vt, ctxb, work_ctr);

    dim3 g3(NROWS / 128, D / 64);
    gemm_out<<<g3, 256, 0, stream>>>(ctxb, wt, bo, out);
}